// Round 7
// baseline (660.108 us; speedup 1.0000x reference)
//
#include <hip/hip_runtime.h>
#include <math.h>

#define D 64

__device__ __forceinline__ float lrelu(float x) { return x >= 0.f ? x : 0.01f * x; }

// ---------------- init: zero edge counters ----------------
__global__ void k_init(int* __restrict__ cnt_u, int nu, int* __restrict__ cnt_i, int ni) {
    int i = blockIdx.x * blockDim.x + threadIdx.x;
    int stride = gridDim.x * blockDim.x;
    for (int j = i; j < nu; j += stride) cnt_u[j] = 0;
    for (int j = i; j < ni; j += stride) cnt_i[j] = 0;
}

// ---------------- per-node GEMVs -> packed [node][64][4] = {hs+hd, hd, ho, pw} ----
__global__ __launch_bounds__(256, 1) void k_nodes(
    const float* __restrict__ X, const float* __restrict__ P,
    const float* __restrict__ Wsrc, const float* __restrict__ bsrc,
    const float* __restrict__ Wdst, const float* __restrict__ bdst,
    const float* __restrict__ Wo,   const float* __restrict__ bo,
    const float* __restrict__ Wu,   const float* __restrict__ bu,
    float4* __restrict__ pack, int n, int npb) {
    __shared__ float sW[4][D * D];      // 64 KB
    __shared__ float sx[4][D], sp[4][D];
    int tid = threadIdx.x;
    for (int t = tid; t < D * D; t += 256) {
        sW[0][t] = Wsrc[t];
        sW[1][t] = Wdst[t];
        sW[2][t] = Wo[t];
        sW[3][t] = Wu[t];
    }
    int lane = tid & 63, g = tid >> 6;
    int base = blockIdx.x * npb;
    float bs = bsrc[lane], bd = bdst[lane], bo_ = bo[lane], bu_ = bu[lane];
    for (int off = 0; off < npb; off += 4) {
        int node = base + off + g;
        bool act = node < n;
        __syncthreads();
        if (act) {
            sx[g][lane] = X[(size_t)node * D + lane];
            sp[g][lane] = P[(size_t)node * D + lane];
        }
        __syncthreads();
        if (act) {
            float a0 = 0.f, a1 = 0.f, a2 = 0.f, a3 = 0.f;
#pragma unroll 8
            for (int k = 0; k < D; ++k) {
                float xk = sx[g][k], pk = sp[g][k];
                a0 += xk * sW[0][k * D + lane];
                a1 += xk * sW[1][k * D + lane];
                a2 += xk * sW[2][k * D + lane];
                a3 += pk * sW[3][k * D + lane];
            }
            float hd = 0.5f * (a1 + bd);
            pack[(size_t)node * D + lane] =
                make_float4(a0 + bs + hd, hd, a2 + bo_, a3 + bu_);
        }
    }
}

// ---------------- pass 1: per-review attention weight + logits + counts ----------
__global__ __launch_bounds__(256, 1) void k_rev1(
    const int* __restrict__ ru, const int* __restrict__ ri,
    const float4* __restrict__ packU, const float4* __restrict__ packI,
    const float* __restrict__ watt_rep, const float* __restrict__ batt_rep,
    const float* __restrict__ watt_agg, const float* __restrict__ batt_agg,
    float* __restrict__ w_u, float* __restrict__ a_ul, float* __restrict__ a_il,
    int* __restrict__ cnt_u, int* __restrict__ cnt_i, int R) {
    int lane = threadIdx.x & 63;
    int r = blockIdx.x * 4 + (threadIdx.x >> 6);
    if (r >= R) return;
    int u = ru[r], it = ri[r];
    float wr = watt_rep[lane], wa = watt_agg[lane];
    float4 pu = packU[(size_t)u * D + lane];   // {hsu+hdu, hdu, hou, pwu}
    float4 pi = packI[(size_t)it * D + lane];  // {hsi+hdi, hdi, hoi, pwi}
    float tu = lrelu(pu.x + pi.y) * wr;
    float ti = lrelu(pi.x + pu.y) * wr;
#pragma unroll
    for (int o = 32; o; o >>= 1) {
        tu += __shfl_xor(tu, o, 64);
        ti += __shfl_xor(ti, o, 64);
    }
    float br = batt_rep[0];
    float a_u = expf(tu + br), a_i = expf(ti + br);
    float wu = a_u / (a_u + a_i), wi = 1.f - wu;
    float ho = wu * pu.z + wi * pi.z;
    float zu = lrelu(ho + pi.w) * wa;  // user-side: pref_item emb
    float zi = lrelu(ho + pu.w) * wa;  // item-side: pref_user emb
#pragma unroll
    for (int o = 32; o; o >>= 1) {
        zu += __shfl_xor(zu, o, 64);
        zi += __shfl_xor(zi, o, 64);
    }
    if (lane == 0) {
        float ba = batt_agg[0];
        w_u[r] = wu;
        a_ul[r] = zu + ba;
        a_il[r] = zi + ba;
        atomicAdd(&cnt_u[u], 1);
        atomicAdd(&cnt_i[it], 1);
    }
}

// ---------------- scan: block 0 scans user counts, block 1 item counts ----------
// cnt[] is overwritten with the running offset (becomes the fill cursor).
__global__ __launch_bounds__(256) void k_scan2(
    int* __restrict__ cnt_u, int* __restrict__ off_u, int nu,
    int* __restrict__ cnt_i, int* __restrict__ off_i, int ni) {
    int* cnt; int* off; int n;
    if (blockIdx.x == 0) { cnt = cnt_u; off = off_u; n = nu; }
    else                 { cnt = cnt_i; off = off_i; n = ni; }
    __shared__ int part[256];
    int t = threadIdx.x;
    int chunk = (n + 255) / 256;
    int b0 = t * chunk, b1 = min(n, b0 + chunk);
    int s = 0;
    for (int j = b0; j < b1; ++j) s += cnt[j];
    part[t] = s;
    __syncthreads();
    for (int o = 1; o < 256; o <<= 1) {
        int v = (t >= o) ? part[t - o] : 0;
        __syncthreads();
        part[t] += v;
        __syncthreads();
    }
    int run = (t == 0) ? 0 : part[t - 1];
    for (int j = b0; j < b1; ++j) {
        int c = cnt[j];
        off[j] = run;
        cnt[j] = run;   // cursor init
        run += c;
    }
    if (t == 255) off[n] = part[255];
}

// ---------------- fill edge lists ----------------
__global__ void k_fill(const int* __restrict__ ru, const int* __restrict__ ri,
                       int* __restrict__ cur_u, int* __restrict__ cur_i,
                       int* __restrict__ eidx_u, int* __restrict__ eidx_i, int R) {
    int r = blockIdx.x * blockDim.x + threadIdx.x;
    if (r >= R) return;
    int p1 = atomicAdd(&cur_u[ru[r]], 1);
    eidx_u[p1] = r;
    int p2 = atomicAdd(&cur_i[ri[r]], 1);
    eidx_i[p2] = r;
}

// ---------------- aggregation: one wave per destination node ----------------
__global__ __launch_bounds__(256, 1) void k_agg(
    const int* __restrict__ off, const int* __restrict__ eidx,
    const int* __restrict__ ridx_other,
    const float* __restrict__ a_arr, const float* __restrict__ w_u,
    const float* __restrict__ Xown, const float* __restrict__ Xother,
    float* __restrict__ out, int n, int own_is_user) {
    int lane = threadIdx.x & 63;
    int d = blockIdx.x * 4 + (threadIdx.x >> 6);
    if (d >= n) return;
    int s = off[d], e = off[d + 1];
    float m = -INFINITY;
    for (int j = s; j < e; ++j) m = fmaxf(m, a_arr[eidx[j]]);
    float ssum = 0.f, coef = 0.f, acc = 0.f;
    for (int j = s; j < e; ++j) {
        int r = eidx[j];
        float ex = expf(a_arr[r] - m);
        float wu = w_u[r];
        float wown = own_is_user ? wu : 1.f - wu;
        ssum += ex;
        coef += ex * wown;
        int o = ridx_other[r];
        acc += ex * (1.f - wown) * Xother[(size_t)o * D + lane];
    }
    float inv = (e > s) ? 1.f / ssum : 0.f;
    out[(size_t)d * D + lane] = (coef * Xown[(size_t)d * D + lane] + acc) * inv;
}

extern "C" void kernel_launch(void* const* d_in, const int* in_sizes, int n_in,
                              void* d_out, int out_size, void* d_ws, size_t ws_size,
                              hipStream_t stream) {
    const float* Xu        = (const float*)d_in[0];
    const float* Xi        = (const float*)d_in[1];
    const float* Wsrc      = (const float*)d_in[2];
    const float* bsrc      = (const float*)d_in[3];
    const float* Wdst      = (const float*)d_in[4];
    const float* bdst      = (const float*)d_in[5];
    const float* watt_rep  = (const float*)d_in[6];
    const float* batt_rep  = (const float*)d_in[7];
    const float* Wo        = (const float*)d_in[8];
    const float* bo        = (const float*)d_in[9];
    const float* Wu        = (const float*)d_in[10];
    const float* bu        = (const float*)d_in[11];
    const float* watt_agg  = (const float*)d_in[12];
    const float* batt_agg  = (const float*)d_in[13];
    const float* pref_user = (const float*)d_in[14];
    const float* pref_item = (const float*)d_in[15];
    const int* r_user      = (const int*)d_in[16];
    const int* r_item      = (const int*)d_in[17];

    int nu = in_sizes[0] / D;
    int ni = in_sizes[1] / D;
    int R  = in_sizes[16];

    float* ws = (float*)d_ws;
    size_t off = 0;
    float4* packU = (float4*)(ws + off); off += (size_t)nu * D * 4;
    float4* packI = (float4*)(ws + off); off += (size_t)ni * D * 4;
    float* w_u  = ws + off; off += (size_t)R;
    float* a_ul = ws + off; off += (size_t)R;
    float* a_il = ws + off; off += (size_t)R;
    int* eidx_u = (int*)(ws + off); off += (size_t)R;
    int* eidx_i = (int*)(ws + off); off += (size_t)R;
    int* cnt_u  = (int*)(ws + off); off += (size_t)nu;       // doubles as cursor
    int* cnt_i  = (int*)(ws + off); off += (size_t)ni;
    int* off_u  = (int*)(ws + off); off += (size_t)nu + 1;
    int* off_i  = (int*)(ws + off); off += (size_t)ni + 1;

    // zero counters
    k_init<<<128, 256, 0, stream>>>(cnt_u, nu, cnt_i, ni);

    // node-level precompute
    const int NPB = 96;
    k_nodes<<<(nu + NPB - 1) / NPB, 256, 0, stream>>>(
        Xu, pref_user, Wsrc, bsrc, Wdst, bdst, Wo, bo, Wu, bu, packU, nu, NPB);
    k_nodes<<<(ni + NPB - 1) / NPB, 256, 0, stream>>>(
        Xi, pref_item, Wsrc, bsrc, Wdst, bdst, Wo, bo, Wu, bu, packI, ni, NPB);

    // per-review attention + counts
    k_rev1<<<(R + 3) / 4, 256, 0, stream>>>(
        r_user, r_item, packU, packI,
        watt_rep, batt_rep, watt_agg, batt_agg,
        w_u, a_ul, a_il, cnt_u, cnt_i, R);

    // offsets
    k_scan2<<<2, 256, 0, stream>>>(cnt_u, off_u, nu, cnt_i, off_i, ni);

    // edge lists
    k_fill<<<(R + 255) / 256, 256, 0, stream>>>(
        r_user, r_item, cnt_u, cnt_i, eidx_u, eidx_i, R);

    // per-destination softmax + weighted sum (no float atomics anywhere)
    k_agg<<<(nu + 3) / 4, 256, 0, stream>>>(
        off_u, eidx_u, r_item, a_ul, w_u, Xu, Xi, (float*)d_out, nu, 1);
    k_agg<<<(ni + 3) / 4, 256, 0, stream>>>(
        off_i, eidx_i, r_user, a_il, w_u, Xi, Xu, (float*)d_out + (size_t)nu * D, ni, 0);
}

// Round 9
// 422.414 us; speedup vs baseline: 1.5627x; 1.5627x over previous
//
#include <hip/hip_runtime.h>
#include <hip/hip_fp16.h>
#include <math.h>

#define D 64
#define TN 32   // nodes per LDS tile in k_nodes

struct __align__(8) h4 { __half2 a; __half2 b; };

__device__ __forceinline__ float lrelu(float x) { return x >= 0.f ? x : 0.01f * x; }

// ---------------- init: zero edge counters ----------------
__global__ void k_init(int* __restrict__ cnt_u, int nu, int* __restrict__ cnt_i, int ni) {
    int i = blockIdx.x * blockDim.x + threadIdx.x;
    int stride = gridDim.x * blockDim.x;
    for (int j = i; j < nu; j += stride) cnt_u[j] = 0;
    for (int j = i; j < ni; j += stride) cnt_i[j] = 0;
}

// ---------------- per-node GEMVs -> packed h4 {hs+hd, hd, ho, pw} ----------------
// 512 threads, 32-node tiles staged in LDS, wave computes 4 nodes (weights shared).
__global__ __launch_bounds__(512, 1) void k_nodes(
    const float* __restrict__ X, const float* __restrict__ P,
    const float* __restrict__ Wsrc, const float* __restrict__ bsrc,
    const float* __restrict__ Wdst, const float* __restrict__ bdst,
    const float* __restrict__ Wo,   const float* __restrict__ bo,
    const float* __restrict__ Wu,   const float* __restrict__ bu,
    h4* __restrict__ pack, int n, int ntiles) {
    __shared__ float sW[4][D * D];        // 64 KB
    __shared__ float sx[TN * D];          // 8 KB
    __shared__ float sp[TN * D];          // 8 KB
    int tid = threadIdx.x;
    for (int t = tid; t < D * D; t += 512) {
        sW[0][t] = Wsrc[t];
        sW[1][t] = Wdst[t];
        sW[2][t] = Wo[t];
        sW[3][t] = Wu[t];
    }
    int lane = tid & 63, w = tid >> 6;    // 8 waves
    float bs = bsrc[lane], bd = bdst[lane], bo_ = bo[lane], bu_ = bu[lane];

    for (int tile = blockIdx.x; tile < ntiles; tile += gridDim.x) {
        int base = tile * TN;
        __syncthreads();
        int nelem = n * D;
        for (int idx = tid; idx < TN * D; idx += 512) {
            int g = base * D + idx;
            if (g < nelem) { sx[idx] = X[g]; sp[idx] = P[g]; }
        }
        __syncthreads();
        int n0 = w * 4;                    // local node base for this wave
        if (base + n0 < n) {
            float acc[4][4] = {{0.f}};
#pragma unroll 4
            for (int k = 0; k < D; ++k) {
                float w0 = sW[0][k * D + lane];
                float w1 = sW[1][k * D + lane];
                float w2 = sW[2][k * D + lane];
                float w3 = sW[3][k * D + lane];
#pragma unroll
                for (int nn = 0; nn < 4; ++nn) {
                    float xk = sx[(n0 + nn) * D + k];   // LDS broadcast
                    float pk = sp[(n0 + nn) * D + k];
                    acc[nn][0] += xk * w0;
                    acc[nn][1] += xk * w1;
                    acc[nn][2] += xk * w2;
                    acc[nn][3] += pk * w3;
                }
            }
#pragma unroll
            for (int nn = 0; nn < 4; ++nn) {
                int node = base + n0 + nn;
                if (node < n) {
                    float hd = 0.5f * (acc[nn][1] + bd);
                    float f0 = acc[nn][0] + bs + hd;
                    float f2 = acc[nn][2] + bo_;
                    float f3 = acc[nn][3] + bu_;
                    h4 o;
                    o.a = __floats2half2_rn(f0, hd);
                    o.b = __floats2half2_rn(f2, f3);
                    pack[(size_t)node * D + lane] = o;
                }
            }
        }
    }
}

// ---------------- pass 1: per-review attention weight + logits + counts ----------
__global__ __launch_bounds__(256, 1) void k_rev1(
    const int* __restrict__ ru, const int* __restrict__ ri,
    const h4* __restrict__ packU, const h4* __restrict__ packI,
    const float* __restrict__ watt_rep, const float* __restrict__ batt_rep,
    const float* __restrict__ watt_agg, const float* __restrict__ batt_agg,
    float* __restrict__ w_u, float* __restrict__ a_ul, float* __restrict__ a_il,
    int* __restrict__ cnt_u, int* __restrict__ cnt_i, int R) {
    int lane = threadIdx.x & 63;
    int r = blockIdx.x * 4 + (threadIdx.x >> 6);
    if (r >= R) return;
    int u = ru[r], it = ri[r];
    float wr = watt_rep[lane], wa = watt_agg[lane];
    h4 qu = packU[(size_t)u * D + lane];   // {hsu+hdu, hdu, hou, pwu}
    h4 qi = packI[(size_t)it * D + lane];  // {hsi+hdi, hdi, hoi, pwi}
    float2 uxy = __half22float2(qu.a), uzw = __half22float2(qu.b);
    float2 ixy = __half22float2(qi.a), izw = __half22float2(qi.b);
    float tu = lrelu(uxy.x + ixy.y) * wr;
    float ti = lrelu(ixy.x + uxy.y) * wr;
#pragma unroll
    for (int o = 32; o; o >>= 1) {
        tu += __shfl_xor(tu, o, 64);
        ti += __shfl_xor(ti, o, 64);
    }
    float br = batt_rep[0];
    float a_u = __expf(tu + br), a_i = __expf(ti + br);
    float wu = a_u / (a_u + a_i), wi = 1.f - wu;
    float ho = wu * uzw.x + wi * izw.x;
    float zu = lrelu(ho + izw.y) * wa;  // user-side: pref_item emb
    float zi = lrelu(ho + uzw.y) * wa;  // item-side: pref_user emb
#pragma unroll
    for (int o = 32; o; o >>= 1) {
        zu += __shfl_xor(zu, o, 64);
        zi += __shfl_xor(zi, o, 64);
    }
    if (lane == 0) {
        float ba = batt_agg[0];
        w_u[r] = wu;
        a_ul[r] = zu + ba;
        a_il[r] = zi + ba;
        atomicAdd(&cnt_u[u], 1);
        atomicAdd(&cnt_i[it], 1);
    }
}

// ---------------- scan: block 0 scans user counts, block 1 item counts ----------
// cnt[] is overwritten with the running offset (becomes the fill cursor).
__global__ __launch_bounds__(256) void k_scan2(
    int* __restrict__ cnt_u, int* __restrict__ off_u, int nu,
    int* __restrict__ cnt_i, int* __restrict__ off_i, int ni) {
    int* cnt; int* off; int n;
    if (blockIdx.x == 0) { cnt = cnt_u; off = off_u; n = nu; }
    else                 { cnt = cnt_i; off = off_i; n = ni; }
    __shared__ int part[256];
    int t = threadIdx.x;
    int chunk = (n + 255) / 256;
    int b0 = t * chunk, b1 = min(n, b0 + chunk);
    int s = 0;
    for (int j = b0; j < b1; ++j) s += cnt[j];
    part[t] = s;
    __syncthreads();
    for (int o = 1; o < 256; o <<= 1) {
        int v = (t >= o) ? part[t - o] : 0;
        __syncthreads();
        part[t] += v;
        __syncthreads();
    }
    int run = (t == 0) ? 0 : part[t - 1];
    for (int j = b0; j < b1; ++j) {
        int c = cnt[j];
        off[j] = run;
        cnt[j] = run;   // cursor init
        run += c;
    }
    if (t == 255) off[n] = part[255];
}

// ---------------- scatter CSR payloads: (a, wu, other) per edge, both sides ----
__global__ void k_scatter(
    const int* __restrict__ ru, const int* __restrict__ ri,
    const float* __restrict__ a_ul, const float* __restrict__ a_il,
    const float* __restrict__ w_u,
    int* __restrict__ cur_u, int* __restrict__ cur_i,
    float* __restrict__ au_su, float* __restrict__ wu_su, int* __restrict__ oi_su,
    float* __restrict__ au_si, float* __restrict__ wu_si, int* __restrict__ oi_si,
    int R) {
    int r = blockIdx.x * blockDim.x + threadIdx.x;
    if (r >= R) return;
    int u = ru[r], it = ri[r];
    float w = w_u[r];
    int j1 = atomicAdd(&cur_u[u], 1);
    au_su[j1] = a_ul[r]; wu_su[j1] = w; oi_su[j1] = it;
    int j2 = atomicAdd(&cur_i[it], 1);
    au_si[j2] = a_il[r]; wu_si[j2] = w; oi_si[j2] = u;
}

// ---------------- aggregation: one wave per destination node, both sides ------
__global__ __launch_bounds__(256, 1) void k_agg(
    const int* __restrict__ off_u, const int* __restrict__ off_i,
    const float* __restrict__ au_su, const float* __restrict__ wu_su, const int* __restrict__ oi_su,
    const float* __restrict__ au_si, const float* __restrict__ wu_si, const int* __restrict__ oi_si,
    const float* __restrict__ Xu, const float* __restrict__ Xi,
    float* __restrict__ out, int nu, int ntot) {
    int lane = threadIdx.x & 63;
    int idx = blockIdx.x * 4 + (threadIdx.x >> 6);
    if (idx >= ntot) return;
    bool user = idx < nu;
    int d = user ? idx : idx - nu;
    const int*   offp = user ? off_u : off_i;
    const float* au   = user ? au_su : au_si;
    const float* wus  = user ? wu_su : wu_si;
    const int*   oi   = user ? oi_su : oi_si;
    const float* Xown = user ? Xu : Xi;
    const float* Xoth = user ? Xi : Xu;
    int s = offp[d], e = offp[d + 1];
    if (s == e) { out[(size_t)idx * D + lane] = 0.f; return; }
    // lane-parallel max
    float mym = -INFINITY;
    for (int j = s + lane; j < e; j += 64) mym = fmaxf(mym, au[j]);
#pragma unroll
    for (int o = 32; o; o >>= 1) mym = fmaxf(mym, __shfl_xor(mym, o, 64));
    float m = mym;
    // lane-parallel sum(exp) and coef = sum(exp * wown)
    float msum = 0.f, mcoef = 0.f;
    for (int j = s + lane; j < e; j += 64) {
        float ex = __expf(au[j] - m);
        float w = wus[j];
        float wown = user ? w : 1.f - w;
        msum += ex;
        mcoef += ex * wown;
    }
#pragma unroll
    for (int o = 32; o; o >>= 1) {
        msum  += __shfl_xor(msum, o, 64);
        mcoef += __shfl_xor(mcoef, o, 64);
    }
    float inv = 1.f / msum;
    // serial edge loop: gather other-side rows
    float acc = 0.f;
#pragma unroll 2
    for (int j = s; j < e; ++j) {
        float a = au[j];
        float w = wus[j];
        int o2 = oi[j];
        float wown = user ? w : 1.f - w;
        float v = __expf(a - m) * inv;
        acc += v * (1.f - wown) * Xoth[(size_t)o2 * D + lane];
    }
    out[(size_t)idx * D + lane] = mcoef * inv * Xown[(size_t)d * D + lane] + acc;
}

extern "C" void kernel_launch(void* const* d_in, const int* in_sizes, int n_in,
                              void* d_out, int out_size, void* d_ws, size_t ws_size,
                              hipStream_t stream) {
    const float* Xu        = (const float*)d_in[0];
    const float* Xi        = (const float*)d_in[1];
    const float* Wsrc      = (const float*)d_in[2];
    const float* bsrc      = (const float*)d_in[3];
    const float* Wdst      = (const float*)d_in[4];
    const float* bdst      = (const float*)d_in[5];
    const float* watt_rep  = (const float*)d_in[6];
    const float* batt_rep  = (const float*)d_in[7];
    const float* Wo        = (const float*)d_in[8];
    const float* bo        = (const float*)d_in[9];
    const float* Wu        = (const float*)d_in[10];
    const float* bu        = (const float*)d_in[11];
    const float* watt_agg  = (const float*)d_in[12];
    const float* batt_agg  = (const float*)d_in[13];
    const float* pref_user = (const float*)d_in[14];
    const float* pref_item = (const float*)d_in[15];
    const int* r_user      = (const int*)d_in[16];
    const int* r_item      = (const int*)d_in[17];

    int nu = in_sizes[0] / D;
    int ni = in_sizes[1] / D;
    int R  = in_sizes[16];

    float* ws = (float*)d_ws;
    size_t off = 0;
    h4* packU = (h4*)(ws + off); off += (size_t)nu * D * 2;   // 8B = 2 floats per elem
    h4* packI = (h4*)(ws + off); off += (size_t)ni * D * 2;
    float* w_u   = ws + off; off += (size_t)R;
    float* a_ul  = ws + off; off += (size_t)R;
    float* a_il  = ws + off; off += (size_t)R;
    float* au_su = ws + off; off += (size_t)R;
    float* wu_su = ws + off; off += (size_t)R;
    int*   oi_su = (int*)(ws + off); off += (size_t)R;
    float* au_si = ws + off; off += (size_t)R;
    float* wu_si = ws + off; off += (size_t)R;
    int*   oi_si = (int*)(ws + off); off += (size_t)R;
    int* cnt_u = (int*)(ws + off); off += (size_t)nu;         // doubles as cursor
    int* cnt_i = (int*)(ws + off); off += (size_t)ni;
    int* off_u = (int*)(ws + off); off += (size_t)nu + 1;
    int* off_i = (int*)(ws + off); off += (size_t)ni + 1;

    // zero counters
    k_init<<<128, 256, 0, stream>>>(cnt_u, nu, cnt_i, ni);

    // node-level precompute (fp16 pack)
    int ntu = (nu + TN - 1) / TN, nti = (ni + TN - 1) / TN;
    k_nodes<<<512, 512, 0, stream>>>(
        Xu, pref_user, Wsrc, bsrc, Wdst, bdst, Wo, bo, Wu, bu, packU, nu, ntu);
    k_nodes<<<512, 512, 0, stream>>>(
        Xi, pref_item, Wsrc, bsrc, Wdst, bdst, Wo, bo, Wu, bu, packI, ni, nti);

    // per-review attention + counts
    k_rev1<<<(R + 3) / 4, 256, 0, stream>>>(
        r_user, r_item, packU, packI,
        watt_rep, batt_rep, watt_agg, batt_agg,
        w_u, a_ul, a_il, cnt_u, cnt_i, R);

    // offsets
    k_scan2<<<2, 256, 0, stream>>>(cnt_u, off_u, nu, cnt_i, off_i, ni);

    // CSR payload scatter
    k_scatter<<<(R + 255) / 256, 256, 0, stream>>>(
        r_user, r_item, a_ul, a_il, w_u, cnt_u, cnt_i,
        au_su, wu_su, oi_su, au_si, wu_si, oi_si, R);

    // per-destination softmax + weighted sum (both sides, sequential CSR reads)
    int ntot = nu + ni;
    k_agg<<<(ntot + 3) / 4, 256, 0, stream>>>(
        off_u, off_i, au_su, wu_su, oi_su, au_si, wu_si, oi_si,
        Xu, Xi, (float*)d_out, nu, ntot);
}

// Round 10
// 313.354 us; speedup vs baseline: 2.1066x; 1.3480x over previous
//
#include <hip/hip_runtime.h>
#include <hip/hip_fp16.h>
#include <math.h>

#define D 64
#define TN 32     // nodes per LDS tile in k_nodes
#define EPB 1024  // elements per scan block (256 threads x 4)

struct __align__(8) h4 { __half2 a; __half2 b; };

__device__ __forceinline__ float lrelu(float x) { return x >= 0.f ? x : 0.01f * x; }

// ---------------- init: zero edge counters ----------------
__global__ void k_init(int* __restrict__ cnt_u, int nu, int* __restrict__ cnt_i, int ni) {
    int i = blockIdx.x * blockDim.x + threadIdx.x;
    int stride = gridDim.x * blockDim.x;
    for (int j = i; j < nu; j += stride) cnt_u[j] = 0;
    for (int j = i; j < ni; j += stride) cnt_i[j] = 0;
}

// ---------------- per-node GEMVs -> packed h4 {hs+hd, hd, ho, pw} ----------------
__global__ __launch_bounds__(512, 1) void k_nodes(
    const float* __restrict__ X, const float* __restrict__ P,
    const float* __restrict__ Wsrc, const float* __restrict__ bsrc,
    const float* __restrict__ Wdst, const float* __restrict__ bdst,
    const float* __restrict__ Wo,   const float* __restrict__ bo,
    const float* __restrict__ Wu,   const float* __restrict__ bu,
    h4* __restrict__ pack, int n, int ntiles) {
    __shared__ float sW[4][D * D];        // 64 KB
    __shared__ float sx[TN * D];          // 8 KB
    __shared__ float sp[TN * D];          // 8 KB
    int tid = threadIdx.x;
    for (int t = tid; t < D * D; t += 512) {
        sW[0][t] = Wsrc[t];
        sW[1][t] = Wdst[t];
        sW[2][t] = Wo[t];
        sW[3][t] = Wu[t];
    }
    int lane = tid & 63, w = tid >> 6;    // 8 waves
    float bs = bsrc[lane], bd = bdst[lane], bo_ = bo[lane], bu_ = bu[lane];

    for (int tile = blockIdx.x; tile < ntiles; tile += gridDim.x) {
        int base = tile * TN;
        __syncthreads();
        int nelem = n * D;
        for (int idx = tid; idx < TN * D; idx += 512) {
            int g = base * D + idx;
            if (g < nelem) { sx[idx] = X[g]; sp[idx] = P[g]; }
        }
        __syncthreads();
        int n0 = w * 4;                    // local node base for this wave
        if (base + n0 < n) {
            float acc[4][4] = {{0.f}};
#pragma unroll 4
            for (int k = 0; k < D; ++k) {
                float w0 = sW[0][k * D + lane];
                float w1 = sW[1][k * D + lane];
                float w2 = sW[2][k * D + lane];
                float w3 = sW[3][k * D + lane];
#pragma unroll
                for (int nn = 0; nn < 4; ++nn) {
                    float xk = sx[(n0 + nn) * D + k];   // LDS broadcast
                    float pk = sp[(n0 + nn) * D + k];
                    acc[nn][0] += xk * w0;
                    acc[nn][1] += xk * w1;
                    acc[nn][2] += xk * w2;
                    acc[nn][3] += pk * w3;
                }
            }
#pragma unroll
            for (int nn = 0; nn < 4; ++nn) {
                int node = base + n0 + nn;
                if (node < n) {
                    float hd = 0.5f * (acc[nn][1] + bd);
                    float f0 = acc[nn][0] + bs + hd;
                    float f2 = acc[nn][2] + bo_;
                    float f3 = acc[nn][3] + bu_;
                    h4 o;
                    o.a = __floats2half2_rn(f0, hd);
                    o.b = __floats2half2_rn(f2, f3);
                    pack[(size_t)node * D + lane] = o;
                }
            }
        }
    }
}

// ---------------- pass 1: per-review attention weight + logits + counts ----------
__global__ __launch_bounds__(256, 1) void k_rev1(
    const int* __restrict__ ru, const int* __restrict__ ri,
    const h4* __restrict__ packU, const h4* __restrict__ packI,
    const float* __restrict__ watt_rep, const float* __restrict__ batt_rep,
    const float* __restrict__ watt_agg, const float* __restrict__ batt_agg,
    float* __restrict__ w_u, float* __restrict__ a_ul, float* __restrict__ a_il,
    int* __restrict__ cnt_u, int* __restrict__ cnt_i, int R) {
    int lane = threadIdx.x & 63;
    int r = blockIdx.x * 4 + (threadIdx.x >> 6);
    if (r >= R) return;
    int u = ru[r], it = ri[r];
    float wr = watt_rep[lane], wa = watt_agg[lane];
    h4 qu = packU[(size_t)u * D + lane];   // {hsu+hdu, hdu, hou, pwu}
    h4 qi = packI[(size_t)it * D + lane];  // {hsi+hdi, hdi, hoi, pwi}
    float2 uxy = __half22float2(qu.a), uzw = __half22float2(qu.b);
    float2 ixy = __half22float2(qi.a), izw = __half22float2(qi.b);
    float tu = lrelu(uxy.x + ixy.y) * wr;
    float ti = lrelu(ixy.x + uxy.y) * wr;
#pragma unroll
    for (int o = 32; o; o >>= 1) {
        tu += __shfl_xor(tu, o, 64);
        ti += __shfl_xor(ti, o, 64);
    }
    float br = batt_rep[0];
    float a_u = __expf(tu + br), a_i = __expf(ti + br);
    float wu = a_u / (a_u + a_i), wi = 1.f - wu;
    float ho = wu * uzw.x + wi * izw.x;
    float zu = lrelu(ho + izw.y) * wa;  // user-side: pref_item emb
    float zi = lrelu(ho + uzw.y) * wa;  // item-side: pref_user emb
#pragma unroll
    for (int o = 32; o; o >>= 1) {
        zu += __shfl_xor(zu, o, 64);
        zi += __shfl_xor(zi, o, 64);
    }
    if (lane == 0) {
        float ba = batt_agg[0];
        w_u[r] = wu;
        a_ul[r] = zu + ba;
        a_il[r] = zi + ba;
        atomicAdd(&cnt_u[u], 1);
        atomicAdd(&cnt_i[it], 1);
    }
}

// ---------------- two-level scan: (a) local 1024-elem scans ----------------
// blocks [0,Bu): users, [Bu,Bu+Bi): items. Writes local exclusive prefixes
// into off[] and per-block totals into bsum[].
__global__ __launch_bounds__(256) void k_scan_local(
    const int* __restrict__ cnt_u, int* __restrict__ off_u, int nu,
    const int* __restrict__ cnt_i, int* __restrict__ off_i, int ni,
    int* __restrict__ bsum, int Bu) {
    int b = blockIdx.x;
    const int* cnt; int* off; int n; int lb;
    if (b < Bu) { cnt = cnt_u; off = off_u; n = nu; lb = b; }
    else        { cnt = cnt_i; off = off_i; n = ni; lb = b - Bu; }
    int t = threadIdx.x;
    int idx0 = lb * EPB + t * 4;
    int v[4];
#pragma unroll
    for (int k = 0; k < 4; ++k) v[k] = (idx0 + k < n) ? cnt[idx0 + k] : 0;
    int s = v[0] + v[1] + v[2] + v[3];
    // wave-inclusive scan of s
    int lane = t & 63, w = t >> 6;
    int x = s;
#pragma unroll
    for (int o = 1; o < 64; o <<= 1) {
        int y = __shfl_up(x, o, 64);
        if (lane >= o) x += y;
    }
    __shared__ int wsum[4];
    if (lane == 63) wsum[w] = x;
    __syncthreads();
    int woff = 0;
    for (int j = 0; j < w; ++j) woff += wsum[j];
    int run = woff + x - s;      // exclusive prefix for this thread
#pragma unroll
    for (int k = 0; k < 4; ++k) {
        if (idx0 + k < n) off[idx0 + k] = run;
        run += v[k];
    }
    if (t == 255) bsum[b] = woff + x;   // block total
}

// ---------------- (b) scan block sums (<=64 per side), write totals ----------
__global__ __launch_bounds__(128) void k_scan_bsum(
    int* __restrict__ bsum, int Bu, int Bi,
    int* __restrict__ tot_u, int* __restrict__ tot_i) {
    int t = threadIdx.x;
    int w = t >> 6, lane = t & 63;
    int B = (w == 0) ? Bu : Bi;
    int* p = (w == 0) ? bsum : bsum + Bu;
    int v = (lane < B) ? p[lane] : 0;
    int x = v;
#pragma unroll
    for (int o = 1; o < 64; o <<= 1) {
        int y = __shfl_up(x, o, 64);
        if (lane >= o) x += y;
    }
    if (lane < B) p[lane] = x - v;               // exclusive block offset
    if (lane == 63) { if (w == 0) *tot_u = x; else *tot_i = x; }
}

// ---------------- (c) add block offsets, init fill cursors ----------------
__global__ __launch_bounds__(256) void k_scan_add(
    int* __restrict__ off_u, int* __restrict__ cur_u, int nu,
    int* __restrict__ off_i, int* __restrict__ cur_i, int ni,
    const int* __restrict__ bsum, int Bu) {
    int b = blockIdx.x;
    int* off; int* cur; int n; int lb;
    if (b < Bu) { off = off_u; cur = cur_u; n = nu; lb = b; }
    else        { off = off_i; cur = cur_i; n = ni; lb = b - Bu; }
    int boff = bsum[b];
    int idx0 = lb * EPB + threadIdx.x * 4;
#pragma unroll
    for (int k = 0; k < 4; ++k) {
        int idx = idx0 + k;
        if (idx < n) {
            int vv = off[idx] + boff;
            off[idx] = vv;
            cur[idx] = vv;
        }
    }
}

// ---------------- scatter CSR payloads: (a, wu, other) per edge, both sides ----
__global__ void k_scatter(
    const int* __restrict__ ru, const int* __restrict__ ri,
    const float* __restrict__ a_ul, const float* __restrict__ a_il,
    const float* __restrict__ w_u,
    int* __restrict__ cur_u, int* __restrict__ cur_i,
    float* __restrict__ au_su, float* __restrict__ wu_su, int* __restrict__ oi_su,
    float* __restrict__ au_si, float* __restrict__ wu_si, int* __restrict__ oi_si,
    int R) {
    int r = blockIdx.x * blockDim.x + threadIdx.x;
    if (r >= R) return;
    int u = ru[r], it = ri[r];
    float w = w_u[r];
    int j1 = atomicAdd(&cur_u[u], 1);
    au_su[j1] = a_ul[r]; wu_su[j1] = w; oi_su[j1] = it;
    int j2 = atomicAdd(&cur_i[it], 1);
    au_si[j2] = a_il[r]; wu_si[j2] = w; oi_si[j2] = u;
}

// ---------------- aggregation: one wave per destination node, both sides ------
__global__ __launch_bounds__(256, 1) void k_agg(
    const int* __restrict__ off_u, const int* __restrict__ off_i,
    const float* __restrict__ au_su, const float* __restrict__ wu_su, const int* __restrict__ oi_su,
    const float* __restrict__ au_si, const float* __restrict__ wu_si, const int* __restrict__ oi_si,
    const float* __restrict__ Xu, const float* __restrict__ Xi,
    float* __restrict__ out, int nu, int ntot) {
    int lane = threadIdx.x & 63;
    int idx = blockIdx.x * 4 + (threadIdx.x >> 6);
    if (idx >= ntot) return;
    bool user = idx < nu;
    int d = user ? idx : idx - nu;
    const int*   offp = user ? off_u : off_i;
    const float* au   = user ? au_su : au_si;
    const float* wus  = user ? wu_su : wu_si;
    const int*   oi   = user ? oi_su : oi_si;
    const float* Xown = user ? Xu : Xi;
    const float* Xoth = user ? Xi : Xu;
    int s = offp[d], e = offp[d + 1];
    if (s == e) { out[(size_t)idx * D + lane] = 0.f; return; }
    // lane-parallel max
    float mym = -INFINITY;
    for (int j = s + lane; j < e; j += 64) mym = fmaxf(mym, au[j]);
#pragma unroll
    for (int o = 32; o; o >>= 1) mym = fmaxf(mym, __shfl_xor(mym, o, 64));
    float m = mym;
    // lane-parallel sum(exp) and coef = sum(exp * wown)
    float msum = 0.f, mcoef = 0.f;
    for (int j = s + lane; j < e; j += 64) {
        float ex = __expf(au[j] - m);
        float w = wus[j];
        float wown = user ? w : 1.f - w;
        msum += ex;
        mcoef += ex * wown;
    }
#pragma unroll
    for (int o = 32; o; o >>= 1) {
        msum  += __shfl_xor(msum, o, 64);
        mcoef += __shfl_xor(mcoef, o, 64);
    }
    float inv = 1.f / msum;
    // serial edge loop: gather other-side rows
    float acc = 0.f;
#pragma unroll 2
    for (int j = s; j < e; ++j) {
        float a = au[j];
        float w = wus[j];
        int o2 = oi[j];
        float wown = user ? w : 1.f - w;
        float v = __expf(a - m) * inv;
        acc += v * (1.f - wown) * Xoth[(size_t)o2 * D + lane];
    }
    out[(size_t)idx * D + lane] = mcoef * inv * Xown[(size_t)d * D + lane] + acc;
}

extern "C" void kernel_launch(void* const* d_in, const int* in_sizes, int n_in,
                              void* d_out, int out_size, void* d_ws, size_t ws_size,
                              hipStream_t stream) {
    const float* Xu        = (const float*)d_in[0];
    const float* Xi        = (const float*)d_in[1];
    const float* Wsrc      = (const float*)d_in[2];
    const float* bsrc      = (const float*)d_in[3];
    const float* Wdst      = (const float*)d_in[4];
    const float* bdst      = (const float*)d_in[5];
    const float* watt_rep  = (const float*)d_in[6];
    const float* batt_rep  = (const float*)d_in[7];
    const float* Wo        = (const float*)d_in[8];
    const float* bo        = (const float*)d_in[9];
    const float* Wu        = (const float*)d_in[10];
    const float* bu        = (const float*)d_in[11];
    const float* watt_agg  = (const float*)d_in[12];
    const float* batt_agg  = (const float*)d_in[13];
    const float* pref_user = (const float*)d_in[14];
    const float* pref_item = (const float*)d_in[15];
    const int* r_user      = (const int*)d_in[16];
    const int* r_item      = (const int*)d_in[17];

    int nu = in_sizes[0] / D;
    int ni = in_sizes[1] / D;
    int R  = in_sizes[16];

    float* ws = (float*)d_ws;
    size_t off = 0;
    h4* packU = (h4*)(ws + off); off += (size_t)nu * D * 2;   // 8B per elem
    h4* packI = (h4*)(ws + off); off += (size_t)ni * D * 2;
    float* w_u   = ws + off; off += (size_t)R;
    float* a_ul  = ws + off; off += (size_t)R;
    float* a_il  = ws + off; off += (size_t)R;
    float* au_su = ws + off; off += (size_t)R;
    float* wu_su = ws + off; off += (size_t)R;
    int*   oi_su = (int*)(ws + off); off += (size_t)R;
    float* au_si = ws + off; off += (size_t)R;
    float* wu_si = ws + off; off += (size_t)R;
    int*   oi_si = (int*)(ws + off); off += (size_t)R;
    int* cnt_u = (int*)(ws + off); off += (size_t)nu;         // doubles as cursor
    int* cnt_i = (int*)(ws + off); off += (size_t)ni;
    int* bsum  = (int*)(ws + off); off += 256;
    int* off_u = (int*)(ws + off); off += (size_t)nu + 1;
    int* off_i = (int*)(ws + off); off += (size_t)ni + 1;

    // zero counters
    k_init<<<128, 256, 0, stream>>>(cnt_u, nu, cnt_i, ni);

    // node-level precompute (fp16 pack)
    int ntu = (nu + TN - 1) / TN, nti = (ni + TN - 1) / TN;
    k_nodes<<<512, 512, 0, stream>>>(
        Xu, pref_user, Wsrc, bsrc, Wdst, bdst, Wo, bo, Wu, bu, packU, nu, ntu);
    k_nodes<<<512, 512, 0, stream>>>(
        Xi, pref_item, Wsrc, bsrc, Wdst, bdst, Wo, bo, Wu, bu, packI, ni, nti);

    // per-review attention + counts
    k_rev1<<<(R + 3) / 4, 256, 0, stream>>>(
        r_user, r_item, packU, packI,
        watt_rep, batt_rep, watt_agg, batt_agg,
        w_u, a_ul, a_il, cnt_u, cnt_i, R);

    // two-level scan (assumes <=64 scan-blocks per side: n <= 65536)
    int Bu = (nu + EPB - 1) / EPB, Bi = (ni + EPB - 1) / EPB;
    k_scan_local<<<Bu + Bi, 256, 0, stream>>>(
        cnt_u, off_u, nu, cnt_i, off_i, ni, bsum, Bu);
    k_scan_bsum<<<1, 128, 0, stream>>>(bsum, Bu, Bi, off_u + nu, off_i + ni);
    k_scan_add<<<Bu + Bi, 256, 0, stream>>>(
        off_u, cnt_u, nu, off_i, cnt_i, ni, bsum, Bu);

    // CSR payload scatter
    k_scatter<<<(R + 255) / 256, 256, 0, stream>>>(
        r_user, r_item, a_ul, a_il, w_u, cnt_u, cnt_i,
        au_su, wu_su, oi_su, au_si, wu_si, oi_si, R);

    // per-destination softmax + weighted sum (both sides, sequential CSR reads)
    int ntot = nu + ni;
    k_agg<<<(ntot + 3) / 4, 256, 0, stream>>>(
        off_u, off_i, au_su, wu_su, oi_su, au_si, wu_si, oi_si,
        Xu, Xi, (float*)d_out, nu, ntot);
}

// Round 12
// 268.560 us; speedup vs baseline: 2.4580x; 1.1668x over previous
//
#include <hip/hip_runtime.h>
#include <hip/hip_fp16.h>
#include <math.h>

#define D 64
#define TN 32     // nodes per LDS tile in k_nodes
#define EPB 1024  // elements per scan block (256 threads x 4)

struct __align__(8) h4 { __half2 a; __half2 b; };

__device__ __forceinline__ float lrelu(float x) { return fmaxf(x, 0.f) + 0.01f * fminf(x, 0.f); }
__device__ __forceinline__ __half2 u2h(unsigned v) { union { unsigned u; __half2 h; } c; c.u = v; return c.h; }

// ---------------- init: zero edge counters ----------------
__global__ void k_init(int* __restrict__ cnt_u, int nu, int* __restrict__ cnt_i, int ni) {
    int i = blockIdx.x * blockDim.x + threadIdx.x;
    int stride = gridDim.x * blockDim.x;
    for (int j = i; j < nu; j += stride) cnt_u[j] = 0;
    for (int j = i; j < ni; j += stride) cnt_i[j] = 0;
}

// ---------------- per-node GEMVs -> packed h4 {hs+hd, hd, ho, pw}; also fp16 X copy ----
__global__ __launch_bounds__(512, 1) void k_nodes(
    const float* __restrict__ X, const float* __restrict__ P,
    const float* __restrict__ Wsrc, const float* __restrict__ bsrc,
    const float* __restrict__ Wdst, const float* __restrict__ bdst,
    const float* __restrict__ Wo,   const float* __restrict__ bo,
    const float* __restrict__ Wu,   const float* __restrict__ bu,
    h4* __restrict__ pack, __half* __restrict__ Xh, int n, int ntiles) {
    __shared__ float sW[4][D * D];        // 64 KB
    __shared__ float sx[TN * D];          // 8 KB
    __shared__ float sp[TN * D];          // 8 KB
    int tid = threadIdx.x;
    for (int t = tid; t < D * D; t += 512) {
        sW[0][t] = Wsrc[t];
        sW[1][t] = Wdst[t];
        sW[2][t] = Wo[t];
        sW[3][t] = Wu[t];
    }
    int lane = tid & 63, w = tid >> 6;    // 8 waves
    float bs = bsrc[lane], bd = bdst[lane], bo_ = bo[lane], bu_ = bu[lane];

    for (int tile = blockIdx.x; tile < ntiles; tile += gridDim.x) {
        int base = tile * TN;
        __syncthreads();
        int nelem = n * D;
        for (int idx = tid; idx < TN * D; idx += 512) {
            int g = base * D + idx;
            if (g < nelem) {
                float vx = X[g], vp = P[g];
                sx[idx] = vx; sp[idx] = vp;
                Xh[g] = __float2half(vx);
            }
        }
        __syncthreads();
        int n0 = w * 4;                    // local node base for this wave
        if (base + n0 < n) {
            float acc[4][4] = {{0.f}};
#pragma unroll 4
            for (int k = 0; k < D; ++k) {
                float w0 = sW[0][k * D + lane];
                float w1 = sW[1][k * D + lane];
                float w2 = sW[2][k * D + lane];
                float w3 = sW[3][k * D + lane];
#pragma unroll
                for (int nn = 0; nn < 4; ++nn) {
                    float xk = sx[(n0 + nn) * D + k];   // LDS broadcast
                    float pk = sp[(n0 + nn) * D + k];
                    acc[nn][0] += xk * w0;
                    acc[nn][1] += xk * w1;
                    acc[nn][2] += xk * w2;
                    acc[nn][3] += pk * w3;
                }
            }
#pragma unroll
            for (int nn = 0; nn < 4; ++nn) {
                int node = base + n0 + nn;
                if (node < n) {
                    float hd = 0.5f * (acc[nn][1] + bd);
                    float f0 = acc[nn][0] + bs + hd;
                    float f2 = acc[nn][2] + bo_;
                    float f3 = acc[nn][3] + bu_;
                    h4 o;
                    o.a = __floats2half2_rn(f0, hd);
                    o.b = __floats2half2_rn(f2, f3);
                    pack[(size_t)node * D + lane] = o;
                }
            }
        }
    }
}

// ---------------- pass 1: 2 reviews per wave, f16 loads + f32 math ----------------
__global__ __launch_bounds__(256, 1) void k_rev1(
    const int* __restrict__ ru, const int* __restrict__ ri,
    const float4* __restrict__ packU4, const float4* __restrict__ packI4,
    const float* __restrict__ watt_rep,
    const float* __restrict__ watt_agg, const float* __restrict__ batt_agg,
    float* __restrict__ w_u, float* __restrict__ a_ul, float* __restrict__ a_il,
    int* __restrict__ cnt_u, int* __restrict__ cnt_i, int R) {
    int tid = threadIdx.x;
    int lane = tid & 63;
    int sub = lane >> 5;          // review slot within wave
    int f = lane & 31;            // feature-pair index (features 2f, 2f+1)
    int r = blockIdx.x * 8 + (tid >> 6) * 2 + sub;
    if (r >= R) return;
    int u = ru[r], it = ri[r];
    // 16B load = two adjacent h4 (features 2f, 2f+1)
    float4 Uv = packU4[(size_t)u * 32 + f];
    float4 Iv = packI4[(size_t)it * 32 + f];
    unsigned ux = __float_as_uint(Uv.x), uy = __float_as_uint(Uv.y);
    unsigned uz = __float_as_uint(Uv.z), uw = __float_as_uint(Uv.w);
    unsigned ix = __float_as_uint(Iv.x), iy = __float_as_uint(Iv.y);
    unsigned iz = __float_as_uint(Iv.z), iw = __float_as_uint(Iv.w);
    __half2 f0u = u2h((ux & 0xFFFFu) | (uz << 16));
    __half2 hdu = u2h((ux >> 16) | (uz & 0xFFFF0000u));
    __half2 hou = u2h((uy & 0xFFFFu) | (uw << 16));
    __half2 pwu = u2h((uy >> 16) | (uw & 0xFFFF0000u));
    __half2 f0i = u2h((ix & 0xFFFFu) | (iz << 16));
    __half2 hdi = u2h((ix >> 16) | (iz & 0xFFFF0000u));
    __half2 hoi = u2h((iy & 0xFFFFu) | (iw << 16));
    __half2 pwi = u2h((iy >> 16) | (iw & 0xFFFF0000u));

    // stage 1: lrelu(hs+hd_sum) . watt_rep  (f32 math)
    float2 xu2 = __half22float2(__hadd2(f0u, hdi));
    float2 xi2 = __half22float2(__hadd2(f0i, hdu));
    float2 wr2 = ((const float2*)watt_rep)[f];
    float tu = lrelu(xu2.x) * wr2.x + lrelu(xu2.y) * wr2.y;
    float ti = lrelu(xi2.x) * wr2.x + lrelu(xi2.y) * wr2.y;
#pragma unroll
    for (int o = 16; o; o >>= 1) {
        tu += __shfl_xor(tu, o, 64);
        ti += __shfl_xor(ti, o, 64);
    }
    // wu = a_u/(a_u+a_i) = sigmoid(tu - ti); batt_rep cancels
    float wu = 1.f / (1.f + __expf(ti - tu));
    // stage 2
    __half2 wu2 = __float2half2_rn(wu);
    __half2 wi2 = __float2half2_rn(1.f - wu);
    __half2 ho = __hfma2(wu2, hou, __hmul2(wi2, hoi));
    float2 su2 = __half22float2(__hadd2(ho, pwi));   // user side: pref_item emb
    float2 si2 = __half22float2(__hadd2(ho, pwu));   // item side: pref_user emb
    float2 wa2 = ((const float2*)watt_agg)[f];
    float zu = lrelu(su2.x) * wa2.x + lrelu(su2.y) * wa2.y;
    float zi = lrelu(si2.x) * wa2.x + lrelu(si2.y) * wa2.y;
#pragma unroll
    for (int o = 16; o; o >>= 1) {
        zu += __shfl_xor(zu, o, 64);
        zi += __shfl_xor(zi, o, 64);
    }
    if (f == 0) {
        float ba = batt_agg[0];
        w_u[r] = wu;
        a_ul[r] = zu + ba;
        a_il[r] = zi + ba;
        atomicAdd(&cnt_u[u], 1);
        atomicAdd(&cnt_i[it], 1);
    }
}

// ---------------- two-level scan: (a) local 1024-elem scans ----------------
__global__ __launch_bounds__(256) void k_scan_local(
    const int* __restrict__ cnt_u, int* __restrict__ off_u, int nu,
    const int* __restrict__ cnt_i, int* __restrict__ off_i, int ni,
    int* __restrict__ bsum, int Bu) {
    int b = blockIdx.x;
    const int* cnt; int* off; int n; int lb;
    if (b < Bu) { cnt = cnt_u; off = off_u; n = nu; lb = b; }
    else        { cnt = cnt_i; off = off_i; n = ni; lb = b - Bu; }
    int t = threadIdx.x;
    int idx0 = lb * EPB + t * 4;
    int v[4];
#pragma unroll
    for (int k = 0; k < 4; ++k) v[k] = (idx0 + k < n) ? cnt[idx0 + k] : 0;
    int s = v[0] + v[1] + v[2] + v[3];
    int lane = t & 63, w = t >> 6;
    int x = s;
#pragma unroll
    for (int o = 1; o < 64; o <<= 1) {
        int y = __shfl_up(x, o, 64);
        if (lane >= o) x += y;
    }
    __shared__ int wsum[4];
    if (lane == 63) wsum[w] = x;
    __syncthreads();
    int woff = 0;
    for (int j = 0; j < w; ++j) woff += wsum[j];
    int run = woff + x - s;      // exclusive prefix for this thread
#pragma unroll
    for (int k = 0; k < 4; ++k) {
        if (idx0 + k < n) off[idx0 + k] = run;
        run += v[k];
    }
    if (t == 255) bsum[b] = woff + x;   // block total
}

// ---------------- (b) scan block sums (<=64 per side), write totals ----------
__global__ __launch_bounds__(128) void k_scan_bsum(
    int* __restrict__ bsum, int Bu, int Bi,
    int* __restrict__ tot_u, int* __restrict__ tot_i) {
    int t = threadIdx.x;
    int w = t >> 6, lane = t & 63;
    int B = (w == 0) ? Bu : Bi;
    int* p = (w == 0) ? bsum : bsum + Bu;
    int v = (lane < B) ? p[lane] : 0;
    int x = v;
#pragma unroll
    for (int o = 1; o < 64; o <<= 1) {
        int y = __shfl_up(x, o, 64);
        if (lane >= o) x += y;
    }
    if (lane < B) p[lane] = x - v;               // exclusive block offset
    if (lane == 63) { if (w == 0) *tot_u = x; else *tot_i = x; }
}

// ---------------- (c) add block offsets, init fill cursors ----------------
__global__ __launch_bounds__(256) void k_scan_add(
    int* __restrict__ off_u, int* __restrict__ cur_u, int nu,
    int* __restrict__ off_i, int* __restrict__ cur_i, int ni,
    const int* __restrict__ bsum, int Bu) {
    int b = blockIdx.x;
    int* off; int* cur; int n; int lb;
    if (b < Bu) { off = off_u; cur = cur_u; n = nu; lb = b; }
    else        { off = off_i; cur = cur_i; n = ni; lb = b - Bu; }
    int boff = bsum[b];
    int idx0 = lb * EPB + threadIdx.x * 4;
#pragma unroll
    for (int k = 0; k < 4; ++k) {
        int idx = idx0 + k;
        if (idx < n) {
            int vv = off[idx] + boff;
            off[idx] = vv;
            cur[idx] = vv;
        }
    }
}

// ---------------- scatter CSR payloads: (a, wu, other) per edge, both sides ----
__global__ void k_scatter(
    const int* __restrict__ ru, const int* __restrict__ ri,
    const float* __restrict__ a_ul, const float* __restrict__ a_il,
    const float* __restrict__ w_u,
    int* __restrict__ cur_u, int* __restrict__ cur_i,
    float* __restrict__ au_su, float* __restrict__ wu_su, int* __restrict__ oi_su,
    float* __restrict__ au_si, float* __restrict__ wu_si, int* __restrict__ oi_si,
    int R) {
    int r = blockIdx.x * blockDim.x + threadIdx.x;
    if (r >= R) return;
    int u = ru[r], it = ri[r];
    float w = w_u[r];
    int j1 = atomicAdd(&cur_u[u], 1);
    au_su[j1] = a_ul[r]; wu_su[j1] = w; oi_su[j1] = it;
    int j2 = atomicAdd(&cur_i[it], 1);
    au_si[j2] = a_il[r]; wu_si[j2] = w; oi_si[j2] = u;
}

// ---------------- aggregation: one wave per destination node, both sides ------
__global__ __launch_bounds__(256, 1) void k_agg(
    const int* __restrict__ off_u, const int* __restrict__ off_i,
    const float* __restrict__ au_su, const float* __restrict__ wu_su, const int* __restrict__ oi_su,
    const float* __restrict__ au_si, const float* __restrict__ wu_si, const int* __restrict__ oi_si,
    const float* __restrict__ Xu, const float* __restrict__ Xi,
    const __half* __restrict__ Xuh, const __half* __restrict__ Xih,
    float* __restrict__ out, int nu, int ntot) {
    int lane = threadIdx.x & 63;
    int idx = blockIdx.x * 4 + (threadIdx.x >> 6);
    if (idx >= ntot) return;
    bool user = idx < nu;
    int d = user ? idx : idx - nu;
    const int*   offp = user ? off_u : off_i;
    const float* au   = user ? au_su : au_si;
    const float* wus  = user ? wu_su : wu_si;
    const int*   oi   = user ? oi_su : oi_si;
    const float* Xown = user ? Xu : Xi;
    const __half* Xoth = user ? Xih : Xuh;
    int s = offp[d], e = offp[d + 1];
    if (s == e) { out[(size_t)idx * D + lane] = 0.f; return; }
    // lane-parallel max
    float mym = -INFINITY;
    for (int j = s + lane; j < e; j += 64) mym = fmaxf(mym, au[j]);
#pragma unroll
    for (int o = 32; o; o >>= 1) mym = fmaxf(mym, __shfl_xor(mym, o, 64));
    float m = mym;
    // lane-parallel sum(exp) and coef = sum(exp * wown)
    float msum = 0.f, mcoef = 0.f;
    for (int j = s + lane; j < e; j += 64) {
        float ex = __expf(au[j] - m);
        float w = wus[j];
        float wown = user ? w : 1.f - w;
        msum += ex;
        mcoef += ex * wown;
    }
#pragma unroll
    for (int o = 32; o; o >>= 1) {
        msum  += __shfl_xor(msum, o, 64);
        mcoef += __shfl_xor(mcoef, o, 64);
    }
    float inv = 1.f / msum;
    // serial edge loop: gather other-side rows (fp16)
    float acc = 0.f;
#pragma unroll 2
    for (int j = s; j < e; ++j) {
        float a = au[j];
        float w = wus[j];
        int o2 = oi[j];
        float wown = user ? w : 1.f - w;
        float v = __expf(a - m) * inv;
        acc += v * (1.f - wown) * __half2float(Xoth[(size_t)o2 * D + lane]);
    }
    out[(size_t)idx * D + lane] = mcoef * inv * Xown[(size_t)d * D + lane] + acc;
}

extern "C" void kernel_launch(void* const* d_in, const int* in_sizes, int n_in,
                              void* d_out, int out_size, void* d_ws, size_t ws_size,
                              hipStream_t stream) {
    const float* Xu        = (const float*)d_in[0];
    const float* Xi        = (const float*)d_in[1];
    const float* Wsrc      = (const float*)d_in[2];
    const float* bsrc      = (const float*)d_in[3];
    const float* Wdst      = (const float*)d_in[4];
    const float* bdst      = (const float*)d_in[5];
    const float* watt_rep  = (const float*)d_in[6];
    const float* batt_rep  = (const float*)d_in[7];  (void)batt_rep; // cancels in sigmoid
    const float* Wo        = (const float*)d_in[8];
    const float* bo        = (const float*)d_in[9];
    const float* Wu        = (const float*)d_in[10];
    const float* bu        = (const float*)d_in[11];
    const float* watt_agg  = (const float*)d_in[12];
    const float* batt_agg  = (const float*)d_in[13];
    const float* pref_user = (const float*)d_in[14];
    const float* pref_item = (const float*)d_in[15];
    const int* r_user      = (const int*)d_in[16];
    const int* r_item      = (const int*)d_in[17];

    int nu = in_sizes[0] / D;
    int ni = in_sizes[1] / D;
    int R  = in_sizes[16];

    float* ws = (float*)d_ws;
    size_t off = 0;
    h4* packU = (h4*)(ws + off); off += (size_t)nu * D * 2;   // 8B per elem
    h4* packI = (h4*)(ws + off); off += (size_t)ni * D * 2;
    __half* Xuh = (__half*)(ws + off); off += (size_t)nu * D / 2;  // 2B per elem
    __half* Xih = (__half*)(ws + off); off += (size_t)ni * D / 2;
    float* w_u   = ws + off; off += (size_t)R;
    float* a_ul  = ws + off; off += (size_t)R;
    float* a_il  = ws + off; off += (size_t)R;
    float* au_su = ws + off; off += (size_t)R;
    float* wu_su = ws + off; off += (size_t)R;
    int*   oi_su = (int*)(ws + off); off += (size_t)R;
    float* au_si = ws + off; off += (size_t)R;
    float* wu_si = ws + off; off += (size_t)R;
    int*   oi_si = (int*)(ws + off); off += (size_t)R;
    int* cnt_u = (int*)(ws + off); off += (size_t)nu;         // doubles as cursor
    int* cnt_i = (int*)(ws + off); off += (size_t)ni;
    int* bsum  = (int*)(ws + off); off += 256;
    int* off_u = (int*)(ws + off); off += (size_t)nu + 1;
    int* off_i = (int*)(ws + off); off += (size_t)ni + 1;

    // zero counters
    k_init<<<128, 256, 0, stream>>>(cnt_u, nu, cnt_i, ni);

    // node-level precompute (fp16 pack + fp16 X copy)
    int ntu = (nu + TN - 1) / TN, nti = (ni + TN - 1) / TN;
    k_nodes<<<512, 512, 0, stream>>>(
        Xu, pref_user, Wsrc, bsrc, Wdst, bdst, Wo, bo, Wu, bu, packU, Xuh, nu, ntu);
    k_nodes<<<512, 512, 0, stream>>>(
        Xi, pref_item, Wsrc, bsrc, Wdst, bdst, Wo, bo, Wu, bu, packI, Xih, ni, nti);

    // per-review attention + counts (2 reviews per wave)
    k_rev1<<<(R + 7) / 8, 256, 0, stream>>>(
        r_user, r_item, (const float4*)packU, (const float4*)packI,
        watt_rep, watt_agg, batt_agg,
        w_u, a_ul, a_il, cnt_u, cnt_i, R);

    // two-level scan (assumes <=64 scan-blocks per side: n <= 65536)
    int Bu = (nu + EPB - 1) / EPB, Bi = (ni + EPB - 1) / EPB;
    k_scan_local<<<Bu + Bi, 256, 0, stream>>>(
        cnt_u, off_u, nu, cnt_i, off_i, ni, bsum, Bu);
    k_scan_bsum<<<1, 128, 0, stream>>>(bsum, Bu, Bi, off_u + nu, off_i + ni);
    k_scan_add<<<Bu + Bi, 256, 0, stream>>>(
        off_u, cnt_u, nu, off_i, cnt_i, ni, bsum, Bu);

    // CSR payload scatter
    k_scatter<<<(R + 255) / 256, 256, 0, stream>>>(
        r_user, r_item, a_ul, a_il, w_u, cnt_u, cnt_i,
        au_su, wu_su, oi_su, au_si, wu_si, oi_si, R);

    // per-destination softmax + weighted sum (both sides, fp16 row gathers)
    int ntot = nu + ni;
    k_agg<<<(ntot + 3) / 4, 256, 0, stream>>>(
        off_u, off_i, au_su, wu_su, oi_su, au_si, wu_si, oi_si,
        Xu, Xi, Xuh, Xih, (float*)d_out, nu, ntot);
}